// Round 8
// baseline (349.098 us; speedup 1.0000x reference)
//
#include <hip/hip_runtime.h>
#include <stdint.h>

#define NROWS 1024
#define NCOLS 16384
#define NRB 64        // row tiles (16 rows each)
#define NCB 16        // col tiles (1024 cols each)
#define TROWS 16      // rows per tile

typedef unsigned long long u64;
typedef unsigned int u32;

// Persistent device state. Everything is written each call before being read:
// partials + col_used/cnt/done by k_scan, rowbest/assigned/rem by k_commit1.
__device__ u64 g_rowpart[NCB * NROWS];         // per col-tile row maxima
__device__ u64 g_colpart[(size_t)NRB * NCOLS]; // per row-tile col maxima (8 MB)
__device__ u64 g_rowbest[NROWS];               // key: (sortable<<32)|(NCOLS-1-col)
__device__ int g_col_used[NCOLS];
__device__ int g_row_assigned[NROWS];
__device__ int g_rem[2][NROWS];                // double-buffered remaining lists
__device__ int g_cnt[3];                       // list counts per round
__device__ int g_done;                         // completion counter (round t=1)

// Monotone float32 -> uint32 mapping (preserves <):
__device__ __forceinline__ u32 fsort(float x) {
    u32 u = __float_as_uint(x);
    return u ^ ((u32)((int)u >> 31) | 0x80000000u);
}

__device__ __forceinline__ u64 wave_reduce_max(u64 v) {
    for (int off = 32; off; off >>= 1) {
        u64 o = __shfl_down(v, off);
        if (o > v) v = o;
    }
    return v;   // valid in lane 0
}

// blockDim == 1024 (16 waves)
__device__ __forceinline__ u64 block_reduce_max_1024(u64 v, u64* s_part) {
    v = wave_reduce_max(v);
    int wave = threadIdx.x >> 6;
    if ((threadIdx.x & 63) == 0) s_part[wave] = v;
    __syncthreads();
    u64 b = s_part[0];
    for (int w = 1; w < 16; w++) if (s_part[w] > b) b = s_part[w];
    __syncthreads();
    return b;
}

// Single-pass scan: grid (NCB, NRB), block 256. Tile = 16 rows x 1024 cols.
// Col maxima in registers (plain stores to colpart); row maxima via per-row
// wave shuffle-reduce. Also absorbs all state init (runs before any reader).
__global__ void __launch_bounds__(256) k_scan(const float* __restrict__ cost) {
    const int tid = threadIdx.x;
    const int wv = tid >> 6, lane = tid & 63;
    const int cb = blockIdx.x, rb = blockIdx.y;
    const int cbase = cb * 1024;
    const int r0 = rb * TROWS;
    const int c0 = cbase + tid * 4;

    if (rb == 0) {     // init: each cb-block zeroes its col_used slice
        int4 z; z.x = 0; z.y = 0; z.z = 0; z.w = 0;
        ((int4*)(g_col_used + cbase))[tid] = z;
        if (cb == 0 && tid < 3) g_cnt[tid] = 0;
        if (cb == 0 && tid == 3) g_done = 0;
    }

    __shared__ u64 s_row[TROWS][4];   // [row-in-tile][wave]

    u64 b0 = 0, b1 = 0, b2 = 0, b3 = 0;
    for (int i = 0; i < TROWS; ++i) {
        int r = r0 + i;
        float4 v = *(const float4*)(cost + (size_t)r * NCOLS + c0);
        u32 rk = (u32)(NROWS - 1 - r);
        u64 k0 = ((u64)fsort(v.x) << 32) | rk;
        u64 k1 = ((u64)fsort(v.y) << 32) | rk;
        u64 k2 = ((u64)fsort(v.z) << 32) | rk;
        u64 k3 = ((u64)fsort(v.w) << 32) | rk;
        if (k0 > b0) b0 = k0;
        if (k1 > b1) b1 = k1;
        if (k2 > b2) b2 = k2;
        if (k3 > b3) b3 = k3;
        // row max for this row: re-key with column id (ties -> smaller col)
        u64 m0 = ((u64)fsort(v.x) << 32) | (u32)(NCOLS - 1 - (c0 + 0));
        u64 m1 = ((u64)fsort(v.y) << 32) | (u32)(NCOLS - 1 - (c0 + 1));
        u64 m2 = ((u64)fsort(v.z) << 32) | (u32)(NCOLS - 1 - (c0 + 2));
        u64 m3 = ((u64)fsort(v.w) << 32) | (u32)(NCOLS - 1 - (c0 + 3));
        u64 m = m0;
        if (m1 > m) m = m1;
        if (m2 > m) m = m2;
        if (m3 > m) m = m3;
        m = wave_reduce_max(m);
        if (lane == 0) s_row[i][wv] = m;
    }
    size_t cp = (size_t)rb * NCOLS + c0;
    g_colpart[cp + 0] = b0;
    g_colpart[cp + 1] = b1;
    g_colpart[cp + 2] = b2;
    g_colpart[cp + 3] = b3;
    __syncthreads();
    if (tid < TROWS) {
        u64 m = s_row[tid][0];
        if (s_row[tid][1] > m) m = s_row[tid][1];
        if (s_row[tid][2] > m) m = s_row[tid][2];
        if (s_row[tid][3] > m) m = s_row[tid][3];
        g_rowpart[cb * NROWS + (r0 + tid)] = m;
    }
}

// Block-per-row, one wave: combine 16 rowparts (redundant 4x, wave-reduced),
// then gather the candidate column's 64 colparts (64 parallel loads) and do
// the round-0 mutual-best commit. Replaces colred + old commit1.
__global__ void __launch_bounds__(64) k_commit1(int* __restrict__ out) {
    int r = blockIdx.x;
    int lane = threadIdx.x;

    u64 v = g_rowpart[(lane & 15) * NROWS + r];
    u64 key = wave_reduce_max(v);
    key = __shfl(key, 0);                       // broadcast
    int c = NCOLS - 1 - (int)(key & 0xFFFFFFFFu);

    u64 cp = g_colpart[(size_t)lane * NCOLS + c];
    u64 colmax = wave_reduce_max(cp);           // lane 0

    if (lane == 0) {
        g_rowbest[r] = key;
        out[r] = r;                             // identity row indices
        u64 mk = (key & 0xFFFFFFFF00000000ULL) | (u32)(NROWS - 1 - r);
        if (colmax == mk) {                     // mutual best -> commit
            g_col_used[c] = 1;
            g_row_assigned[r] = 1;
            out[NROWS + r] = c;
        } else {
            g_row_assigned[r] = 0;
            int p = atomicAdd(&g_cnt[0], 1);
            g_rem[0][p] = r;
        }
    }
}

// Per-round kernel: block r = row r, 1024 threads. (a) rescan own row if its
// cached best col was taken; (b) winner check against raw cost of all rows
// remaining at round start (benign within-round races: conservative losers
// retry). When `last`, the final block to finish runs the general serial
// mop-up loop (threadfence + device-atomic completion counter).
__global__ void __launch_bounds__(1024) k_round(const float* __restrict__ cost,
                                                int* __restrict__ out,
                                                int t, int last) {
    __shared__ u64 s_part[16];
    __shared__ int s_last;
    __shared__ int s_rem[2][NROWS];
    __shared__ int s_n, s_newn;
    const int r = blockIdx.x;
    const int tid = threadIdx.x;

    if (!g_row_assigned[r]) {
        u64 key = g_rowbest[r];
        int c = NCOLS - 1 - (int)(key & 0xFFFFFFFFu);
        if (g_col_used[c]) {          // stale -> rescan excluding used cols
            u64 best = 0ULL;
            const float4* row = (const float4*)(cost + (size_t)r * NCOLS);
            const int4* used = (const int4*)g_col_used;
            for (int k = tid; k < NCOLS / 4; k += 1024) {
                float4 v = row[k];
                int4 u = used[k];
                int c0 = k * 4;
                if (!u.x) { u64 kk = ((u64)fsort(v.x) << 32) | (u32)(NCOLS - 1 - (c0 + 0)); if (kk > best) best = kk; }
                if (!u.y) { u64 kk = ((u64)fsort(v.y) << 32) | (u32)(NCOLS - 1 - (c0 + 1)); if (kk > best) best = kk; }
                if (!u.z) { u64 kk = ((u64)fsort(v.z) << 32) | (u32)(NCOLS - 1 - (c0 + 2)); if (kk > best) best = kk; }
                if (!u.w) { u64 kk = ((u64)fsort(v.w) << 32) | (u32)(NCOLS - 1 - (c0 + 3)); if (kk > best) best = kk; }
            }
            key = block_reduce_max_1024(best, s_part);
            if (tid == 0) g_rowbest[r] = key;
            c = NCOLS - 1 - (int)(key & 0xFFFFFFFFu);
        }

        int n = g_cnt[t];
        const int* list = g_rem[t & 1];
        u64 mine = (key & 0xFFFFFFFF00000000ULL) | (u32)(NROWS - 1 - r);
        u64 mx = 0ULL;
        for (int j = tid; j < n; j += 1024) {
            int rj = list[j];
            if (rj != r) {
                float x = cost[(size_t)rj * NCOLS + c];
                u64 kj = ((u64)fsort(x) << 32) | (u32)(NROWS - 1 - rj);
                if (kj > mx) mx = kj;
            }
        }
        mx = block_reduce_max_1024(mx, s_part);
        if (tid == 0) {
            if (mine > mx) {          // unique max at col c among survivors
                g_col_used[c] = 1;
                g_row_assigned[r] = 1;
                out[NROWS + r] = c;
            } else {
                int p = atomicAdd(&g_cnt[t + 1], 1);
                g_rem[(t + 1) & 1][p] = r;
            }
        }
    }

    if (!last) return;

    // ---- completion detection: last block runs the general finish loop ----
    __syncthreads();
    __threadfence();                  // release this block's writes
    if (tid == 0) {
        int d = atomicAdd(&g_done, 1);
        s_last = (d == (int)gridDim.x - 1);
    }
    __syncthreads();
    if (!s_last) return;
    __threadfence();                  // acquire other blocks' writes

    int n = g_cnt[t + 1];
    if (n == 0) return;
    for (int i = tid; i < n; i += 1024) s_rem[0][i] = g_rem[(t + 1) & 1][i];
    __syncthreads();
    int cur = 0;
    while (n > 0) {
        // recompute stale rows (serially over rows, parallel over cols)
        for (int i = 0; i < n; i++) {
            int rr = s_rem[cur][i];
            u64 key = g_rowbest[rr];
            int c = NCOLS - 1 - (int)(key & 0xFFFFFFFFu);
            if (g_col_used[c]) {
                u64 best = 0ULL;
                const float4* row = (const float4*)(cost + (size_t)rr * NCOLS);
                const int4* used = (const int4*)g_col_used;
                for (int k = tid; k < NCOLS / 4; k += 1024) {
                    float4 v = row[k];
                    int4 u = used[k];
                    int c0 = k * 4;
                    if (!u.x) { u64 kk = ((u64)fsort(v.x) << 32) | (u32)(NCOLS - 1 - (c0 + 0)); if (kk > best) best = kk; }
                    if (!u.y) { u64 kk = ((u64)fsort(v.y) << 32) | (u32)(NCOLS - 1 - (c0 + 1)); if (kk > best) best = kk; }
                    if (!u.z) { u64 kk = ((u64)fsort(v.z) << 32) | (u32)(NCOLS - 1 - (c0 + 2)); if (kk > best) best = kk; }
                    if (!u.w) { u64 kk = ((u64)fsort(v.w) << 32) | (u32)(NCOLS - 1 - (c0 + 3)); if (kk > best) best = kk; }
                }
                u64 bb = block_reduce_max_1024(best, s_part);
                if (tid == 0) g_rowbest[rr] = bb;
                __syncthreads();
            }
        }
        __syncthreads();

        // winner check (thread per listed row, serial inner loop — n is small)
        bool win = false; int myr = -1, myc = -1;
        if (tid < n) {
            int rr = s_rem[cur][tid];
            u64 key = g_rowbest[rr];
            int c = NCOLS - 1 - (int)(key & 0xFFFFFFFFu);
            u64 mine = (key & 0xFFFFFFFF00000000ULL) | (u32)(NROWS - 1 - rr);
            win = true;
            for (int j = 0; j < n; j++) {
                int rj = s_rem[cur][j];
                if (rj == rr) continue;
                float x = cost[(size_t)rj * NCOLS + c];
                u64 kj = ((u64)fsort(x) << 32) | (u32)(NROWS - 1 - rj);
                if (kj > mine) { win = false; break; }
            }
            myr = rr; myc = c;
        }
        __syncthreads();
        if (win) {
            g_col_used[myc] = 1;
            g_row_assigned[myr] = 1;
            out[NROWS + myr] = myc;
        }
        if (tid == 0) s_newn = 0;
        __syncthreads();
        if (tid < n && !win) {
            int p = atomicAdd(&s_newn, 1);
            s_rem[cur ^ 1][p] = myr;
        }
        __syncthreads();
        n = s_newn;
        cur ^= 1;
        __syncthreads();
    }
}

extern "C" void kernel_launch(void* const* d_in, const int* in_sizes, int n_in,
                              void* d_out, int out_size, void* d_ws, size_t ws_size,
                              hipStream_t stream) {
    const float* cost = (const float*)d_in[0];
    int* out = (int*)d_out;

    k_scan<<<dim3(NCB, NRB), 256, 0, stream>>>(cost);
    k_commit1<<<NROWS, 64, 0, stream>>>(out);
    k_round<<<NROWS, 1024, 0, stream>>>(cost, out, 0, 0);
    k_round<<<NROWS, 1024, 0, stream>>>(cost, out, 1, 1);
}

// Round 9
// 129.713 us; speedup vs baseline: 2.6913x; 2.6913x over previous
//
#include <hip/hip_runtime.h>
#include <stdint.h>

#define NROWS 1024
#define NCOLS 16384
#define NRB 64        // row tiles (16 rows each)
#define NCB 16        // col tiles (1024 cols each)
#define TROWS 16      // rows per tile
#define NROUNDS 2

typedef unsigned long long u64;
typedef unsigned int u32;

// Persistent device state. Everything is written each call before being read:
// partials + col_used/cnt by k_scan; rowbest/assigned/rem by k_commit1.
__device__ u64 g_rowpart[NCB * NROWS];         // per col-tile row maxima
__device__ u64 g_colpart[(size_t)NRB * NCOLS]; // per row-tile col maxima (8 MB)
__device__ u64 g_rowbest[NROWS];               // key: (sortable<<32)|(NCOLS-1-col)
__device__ int g_col_used[NCOLS];
__device__ int g_row_assigned[NROWS];
__device__ int g_rem[2][NROWS];                // double-buffered remaining lists
__device__ int g_cnt[NROUNDS + 1];             // list counts per round

// Monotone float32 -> uint32 mapping (preserves <):
__device__ __forceinline__ u32 fsort(float x) {
    u32 u = __float_as_uint(x);
    return u ^ ((u32)((int)u >> 31) | 0x80000000u);
}

__device__ __forceinline__ u64 wave_reduce_max(u64 v) {
    for (int off = 32; off; off >>= 1) {
        u64 o = __shfl_down(v, off);
        if (o > v) v = o;
    }
    return v;   // valid in lane 0
}

// blockDim == 256 (4 waves)
__device__ __forceinline__ u64 block_reduce_max(u64 v, u64* s_part) {
    v = wave_reduce_max(v);
    int wave = threadIdx.x >> 6;
    if ((threadIdx.x & 63) == 0) s_part[wave] = v;
    __syncthreads();
    u64 b = s_part[0];
    for (int w = 1; w < 4; w++) if (s_part[w] > b) b = s_part[w];
    __syncthreads();
    return b;
}

// Single-pass scan: grid (NCB, NRB), block 256. Tile = 16 rows x 1024 cols.
// Col maxima in registers (plain stores to colpart); row maxima via per-row
// wave shuffle-reduce. Also absorbs all state init (runs before any reader;
// kernel boundary orders it for later dispatches).
__global__ void __launch_bounds__(256) k_scan(const float* __restrict__ cost) {
    const int tid = threadIdx.x;
    const int wv = tid >> 6, lane = tid & 63;
    const int cb = blockIdx.x, rb = blockIdx.y;
    const int cbase = cb * 1024;
    const int r0 = rb * TROWS;
    const int c0 = cbase + tid * 4;

    if (rb == 0) {     // init: each cb-block zeroes its col_used slice
        int4 z; z.x = 0; z.y = 0; z.z = 0; z.w = 0;
        ((int4*)(g_col_used + cbase))[tid] = z;
        if (cb == 0 && tid <= NROUNDS) g_cnt[tid] = 0;
    }

    __shared__ u64 s_row[TROWS][4];   // [row-in-tile][wave]

    u64 b0 = 0, b1 = 0, b2 = 0, b3 = 0;
    for (int i = 0; i < TROWS; ++i) {
        int r = r0 + i;
        float4 v = *(const float4*)(cost + (size_t)r * NCOLS + c0);
        u32 rk = (u32)(NROWS - 1 - r);
        u64 k0 = ((u64)fsort(v.x) << 32) | rk;
        u64 k1 = ((u64)fsort(v.y) << 32) | rk;
        u64 k2 = ((u64)fsort(v.z) << 32) | rk;
        u64 k3 = ((u64)fsort(v.w) << 32) | rk;
        if (k0 > b0) b0 = k0;
        if (k1 > b1) b1 = k1;
        if (k2 > b2) b2 = k2;
        if (k3 > b3) b3 = k3;
        // row max for this row: re-key with column id (ties -> smaller col)
        u64 m0 = ((u64)fsort(v.x) << 32) | (u32)(NCOLS - 1 - (c0 + 0));
        u64 m1 = ((u64)fsort(v.y) << 32) | (u32)(NCOLS - 1 - (c0 + 1));
        u64 m2 = ((u64)fsort(v.z) << 32) | (u32)(NCOLS - 1 - (c0 + 2));
        u64 m3 = ((u64)fsort(v.w) << 32) | (u32)(NCOLS - 1 - (c0 + 3));
        u64 m = m0;
        if (m1 > m) m = m1;
        if (m2 > m) m = m2;
        if (m3 > m) m = m3;
        m = wave_reduce_max(m);
        if (lane == 0) s_row[i][wv] = m;
    }
    size_t cp = (size_t)rb * NCOLS + c0;
    g_colpart[cp + 0] = b0;
    g_colpart[cp + 1] = b1;
    g_colpart[cp + 2] = b2;
    g_colpart[cp + 3] = b3;
    __syncthreads();
    if (tid < TROWS) {
        u64 m = s_row[tid][0];
        if (s_row[tid][1] > m) m = s_row[tid][1];
        if (s_row[tid][2] > m) m = s_row[tid][2];
        if (s_row[tid][3] > m) m = s_row[tid][3];
        g_rowpart[cb * NROWS + (r0 + tid)] = m;
    }
}

// Block-per-row, one wave: combine 16 rowparts (redundant 4x, wave-reduced),
// then gather the candidate column's 64 colparts (64 parallel loads) and do
// the round-0 mutual-best commit. Merges colred + commit1 in one dispatch.
__global__ void __launch_bounds__(64) k_commit1(int* __restrict__ out) {
    int r = blockIdx.x;
    int lane = threadIdx.x;

    u64 v = g_rowpart[(lane & 15) * NROWS + r];
    u64 key = wave_reduce_max(v);
    key = __shfl(key, 0);                       // broadcast
    int c = NCOLS - 1 - (int)(key & 0xFFFFFFFFu);

    u64 cp = g_colpart[(size_t)lane * NCOLS + c];
    u64 colmax = wave_reduce_max(cp);           // lane 0

    if (lane == 0) {
        g_rowbest[r] = key;
        out[r] = r;                             // identity row indices
        u64 mk = (key & 0xFFFFFFFF00000000ULL) | (u32)(NROWS - 1 - r);
        if (colmax == mk) {                     // mutual best -> commit
            g_col_used[c] = 1;
            g_row_assigned[r] = 1;
            out[NROWS + r] = c;
        } else {
            g_row_assigned[r] = 0;
            int p = atomicAdd(&g_cnt[0], 1);
            g_rem[0][p] = r;
        }
    }
}

// Per-round kernel (R7 shape, 256 threads): block r = row r. Assigned rows
// exit instantly. (a) rescan own row if cached best col was taken; (b) winner
// check against raw cost values of rows remaining at round start. Within-round
// col_used races are benign (conservative losers retry next round).
__global__ void __launch_bounds__(256) k_round(const float* __restrict__ cost,
                                               int* __restrict__ out, int t) {
    int r = blockIdx.x;
    if (g_row_assigned[r]) return;
    int tid = threadIdx.x;
    __shared__ u64 s_part[4];

    u64 key = g_rowbest[r];
    int c = NCOLS - 1 - (int)(key & 0xFFFFFFFFu);
    if (g_col_used[c]) {              // stale -> rescan excluding used cols
        u64 best = 0ULL;
        const float4* row = (const float4*)(cost + (size_t)r * NCOLS);
        const int4* used = (const int4*)g_col_used;
        for (int k = tid; k < NCOLS / 4; k += 256) {
            float4 v = row[k];
            int4 u = used[k];
            int c0 = k * 4;
            if (!u.x) { u64 kk = ((u64)fsort(v.x) << 32) | (u32)(NCOLS - 1 - (c0 + 0)); if (kk > best) best = kk; }
            if (!u.y) { u64 kk = ((u64)fsort(v.y) << 32) | (u32)(NCOLS - 1 - (c0 + 1)); if (kk > best) best = kk; }
            if (!u.z) { u64 kk = ((u64)fsort(v.z) << 32) | (u32)(NCOLS - 1 - (c0 + 2)); if (kk > best) best = kk; }
            if (!u.w) { u64 kk = ((u64)fsort(v.w) << 32) | (u32)(NCOLS - 1 - (c0 + 3)); if (kk > best) best = kk; }
        }
        key = block_reduce_max(best, s_part);
        if (tid == 0) g_rowbest[r] = key;
        c = NCOLS - 1 - (int)(key & 0xFFFFFFFFu);
    }

    int n = g_cnt[t];
    const int* list = g_rem[t & 1];
    u64 mine = (key & 0xFFFFFFFF00000000ULL) | (u32)(NROWS - 1 - r);
    u64 mx = 0ULL;
    for (int j = tid; j < n; j += 256) {
        int rj = list[j];
        if (rj != r) {
            float x = cost[(size_t)rj * NCOLS + c];
            u64 kj = ((u64)fsort(x) << 32) | (u32)(NROWS - 1 - rj);
            if (kj > mx) mx = kj;
        }
    }
    mx = block_reduce_max(mx, s_part);
    if (tid == 0) {
        if (mine > mx) {              // unique max at col c among survivors
            g_col_used[c] = 1;
            g_row_assigned[r] = 1;
            out[NROWS + r] = c;
        } else {
            int p = atomicAdd(&g_cnt[t + 1], 1);
            g_rem[(t + 1) & 1][p] = r;
        }
    }
}

// Correctness fallback: persistent single-block loop (normally sees n==0 or
// tiny n and exits in microseconds).
__global__ void __launch_bounds__(1024) k_finish(const float* __restrict__ cost,
                                                 int* __restrict__ out) {
    __shared__ int s_rem[2][NROWS];
    __shared__ int s_n, s_newn;
    __shared__ u64 s_part2[16];
    int tid = threadIdx.x;
    if (tid == 0) s_n = g_cnt[NROUNDS];
    __syncthreads();
    int n = s_n;
    if (n == 0) return;
    for (int i = tid; i < n; i += blockDim.x) s_rem[0][i] = g_rem[NROUNDS & 1][i];
    __syncthreads();
    int cur = 0;
    while (n > 0) {
        for (int i = 0; i < n; i++) {
            int r = s_rem[cur][i];
            u64 key = g_rowbest[r];
            int c = NCOLS - 1 - (int)(key & 0xFFFFFFFFu);
            if (g_col_used[c]) {
                u64 best = 0ULL;
                const float4* row = (const float4*)(cost + (size_t)r * NCOLS);
                for (int k = tid; k < NCOLS / 4; k += blockDim.x) {
                    float4 v = row[k];
                    int c0 = k * 4;
                    if (!g_col_used[c0 + 0]) { u64 kk = ((u64)fsort(v.x) << 32) | (u32)(NCOLS - 1 - (c0 + 0)); if (kk > best) best = kk; }
                    if (!g_col_used[c0 + 1]) { u64 kk = ((u64)fsort(v.y) << 32) | (u32)(NCOLS - 1 - (c0 + 1)); if (kk > best) best = kk; }
                    if (!g_col_used[c0 + 2]) { u64 kk = ((u64)fsort(v.z) << 32) | (u32)(NCOLS - 1 - (c0 + 2)); if (kk > best) best = kk; }
                    if (!g_col_used[c0 + 3]) { u64 kk = ((u64)fsort(v.w) << 32) | (u32)(NCOLS - 1 - (c0 + 3)); if (kk > best) best = kk; }
                }
                for (int off = 32; off; off >>= 1) {
                    u64 o = __shfl_down(best, off);
                    if (o > best) best = o;
                }
                int wave = tid >> 6;
                if ((tid & 63) == 0) s_part2[wave] = best;
                __syncthreads();
                if (tid == 0) {
                    u64 b = s_part2[0];
                    for (int w = 1; w < 16; w++) if (s_part2[w] > b) b = s_part2[w];
                    g_rowbest[r] = b;
                }
                __syncthreads();
            }
        }
        __syncthreads();
        bool win = false; int myr = -1, myc = -1;
        if (tid < n) {
            int r = s_rem[cur][tid];
            u64 key = g_rowbest[r];
            int c = NCOLS - 1 - (int)(key & 0xFFFFFFFFu);
            u64 mine = (key & 0xFFFFFFFF00000000ULL) | (u32)(NROWS - 1 - r);
            win = true;
            for (int j = 0; j < n; j++) {
                int rj = s_rem[cur][j];
                if (rj == r) continue;
                float x = cost[(size_t)rj * NCOLS + c];
                u64 kj = ((u64)fsort(x) << 32) | (u32)(NROWS - 1 - rj);
                if (kj > mine) { win = false; break; }
            }
            myr = r; myc = c;
        }
        __syncthreads();
        if (win) {
            g_col_used[myc] = 1; g_row_assigned[myr] = 1; out[NROWS + myr] = myc;
        }
        if (tid == 0) s_newn = 0;
        __syncthreads();
        if (tid < n && !win) {
            int p = atomicAdd(&s_newn, 1);
            s_rem[cur ^ 1][p] = myr;
        }
        __syncthreads();
        n = s_newn;
        cur ^= 1;
        __syncthreads();
    }
}

extern "C" void kernel_launch(void* const* d_in, const int* in_sizes, int n_in,
                              void* d_out, int out_size, void* d_ws, size_t ws_size,
                              hipStream_t stream) {
    const float* cost = (const float*)d_in[0];
    int* out = (int*)d_out;

    k_scan<<<dim3(NCB, NRB), 256, 0, stream>>>(cost);
    k_commit1<<<NROWS, 64, 0, stream>>>(out);
    k_round<<<NROWS, 256, 0, stream>>>(cost, out, 0);
    k_round<<<NROWS, 256, 0, stream>>>(cost, out, 1);
    k_finish<<<1, 1024, 0, stream>>>(cost, out);
}

// Round 10
// 128.544 us; speedup vs baseline: 2.7158x; 1.0091x over previous
//
#include <hip/hip_runtime.h>
#include <stdint.h>

#define NROWS 1024
#define NCOLS 16384
#define NRB 128       // row tiles (8 rows each)
#define NCB 16        // col tiles (1024 cols each)
#define TROWS 8       // rows per tile
#define NROUNDS 2

typedef unsigned long long u64;
typedef unsigned int u32;

// Persistent device state. Everything is written each call before being read:
// partials + col_used/cnt by k_scan; rowbest/assigned/rem by k_commit1.
__device__ u64 g_rowpart[NCB * NROWS];         // per col-tile row maxima
__device__ u64 g_colpart[(size_t)NRB * NCOLS]; // per row-tile col maxima (16 MB)
__device__ u64 g_rowbest[NROWS];               // key: (sortable<<32)|(NCOLS-1-col)
__device__ int g_col_used[NCOLS];
__device__ int g_row_assigned[NROWS];
__device__ int g_rem[2][NROWS];                // double-buffered remaining lists
__device__ int g_cnt[NROUNDS + 1];             // list counts per round

// Monotone float32 -> uint32 mapping (preserves <):
__device__ __forceinline__ u32 fsort(float x) {
    u32 u = __float_as_uint(x);
    return u ^ ((u32)((int)u >> 31) | 0x80000000u);
}

__device__ __forceinline__ u64 wave_reduce_max(u64 v) {
    for (int off = 32; off; off >>= 1) {
        u64 o = __shfl_down(v, off);
        if (o > v) v = o;
    }
    return v;   // valid in lane 0
}

// blockDim == 256 (4 waves)
__device__ __forceinline__ u64 block_reduce_max(u64 v, u64* s_part) {
    v = wave_reduce_max(v);
    int wave = threadIdx.x >> 6;
    if ((threadIdx.x & 63) == 0) s_part[wave] = v;
    __syncthreads();
    u64 b = s_part[0];
    for (int w = 1; w < 4; w++) if (s_part[w] > b) b = s_part[w];
    __syncthreads();
    return b;
}

// Single-pass scan: grid (NCB, NRB), block 256. Tile = 8 rows x 1024 cols.
// 2048 blocks = 8 blocks/CU = 32 waves/CU for max HBM latency hiding.
// Col maxima in registers (plain stores to colpart); row maxima via per-row
// wave shuffle-reduce. Absorbs all state init (kernel boundary orders it).
__global__ void __launch_bounds__(256) k_scan(const float* __restrict__ cost) {
    const int tid = threadIdx.x;
    const int wv = tid >> 6, lane = tid & 63;
    const int cb = blockIdx.x, rb = blockIdx.y;
    const int cbase = cb * 1024;
    const int r0 = rb * TROWS;
    const int c0 = cbase + tid * 4;

    if (rb == 0) {     // init: each cb-block zeroes its col_used slice
        int4 z; z.x = 0; z.y = 0; z.z = 0; z.w = 0;
        ((int4*)(g_col_used + cbase))[tid] = z;
        if (cb == 0 && tid <= NROUNDS) g_cnt[tid] = 0;
    }

    __shared__ u64 s_row[TROWS][4];   // [row-in-tile][wave]

    u64 b0 = 0, b1 = 0, b2 = 0, b3 = 0;
    for (int i = 0; i < TROWS; ++i) {
        int r = r0 + i;
        float4 v = *(const float4*)(cost + (size_t)r * NCOLS + c0);
        u32 rk = (u32)(NROWS - 1 - r);
        u64 k0 = ((u64)fsort(v.x) << 32) | rk;
        u64 k1 = ((u64)fsort(v.y) << 32) | rk;
        u64 k2 = ((u64)fsort(v.z) << 32) | rk;
        u64 k3 = ((u64)fsort(v.w) << 32) | rk;
        if (k0 > b0) b0 = k0;
        if (k1 > b1) b1 = k1;
        if (k2 > b2) b2 = k2;
        if (k3 > b3) b3 = k3;
        // row max for this row: re-key with column id (ties -> smaller col)
        u64 m0 = ((u64)fsort(v.x) << 32) | (u32)(NCOLS - 1 - (c0 + 0));
        u64 m1 = ((u64)fsort(v.y) << 32) | (u32)(NCOLS - 1 - (c0 + 1));
        u64 m2 = ((u64)fsort(v.z) << 32) | (u32)(NCOLS - 1 - (c0 + 2));
        u64 m3 = ((u64)fsort(v.w) << 32) | (u32)(NCOLS - 1 - (c0 + 3));
        u64 m = m0;
        if (m1 > m) m = m1;
        if (m2 > m) m = m2;
        if (m3 > m) m = m3;
        m = wave_reduce_max(m);
        if (lane == 0) s_row[i][wv] = m;
    }
    size_t cp = (size_t)rb * NCOLS + c0;
    g_colpart[cp + 0] = b0;
    g_colpart[cp + 1] = b1;
    g_colpart[cp + 2] = b2;
    g_colpart[cp + 3] = b3;
    __syncthreads();
    if (tid < TROWS) {
        u64 m = s_row[tid][0];
        if (s_row[tid][1] > m) m = s_row[tid][1];
        if (s_row[tid][2] > m) m = s_row[tid][2];
        if (s_row[tid][3] > m) m = s_row[tid][3];
        g_rowpart[cb * NROWS + (r0 + tid)] = m;
    }
}

// Block-per-row, one wave: combine 16 rowparts (redundant 4x, wave-reduced),
// then gather the candidate column's 128 colparts (2 per lane) and do the
// round-0 mutual-best commit. Merges colred + commit1 in one dispatch.
__global__ void __launch_bounds__(64) k_commit1(int* __restrict__ out) {
    int r = blockIdx.x;
    int lane = threadIdx.x;

    u64 v = g_rowpart[(lane & 15) * NROWS + r];
    u64 key = wave_reduce_max(v);
    key = __shfl(key, 0);                       // broadcast
    int c = NCOLS - 1 - (int)(key & 0xFFFFFFFFu);

    u64 cp0 = g_colpart[(size_t)lane * NCOLS + c];
    u64 cp1 = g_colpart[(size_t)(lane + 64) * NCOLS + c];
    u64 cp = cp0 > cp1 ? cp0 : cp1;
    u64 colmax = wave_reduce_max(cp);           // lane 0

    if (lane == 0) {
        g_rowbest[r] = key;
        out[r] = r;                             // identity row indices
        u64 mk = (key & 0xFFFFFFFF00000000ULL) | (u32)(NROWS - 1 - r);
        if (colmax == mk) {                     // mutual best -> commit
            g_col_used[c] = 1;
            g_row_assigned[r] = 1;
            out[NROWS + r] = c;
        } else {
            g_row_assigned[r] = 0;
            int p = atomicAdd(&g_cnt[0], 1);
            g_rem[0][p] = r;
        }
    }
}

// Per-round kernel (256 threads): block r = row r. Assigned rows exit
// instantly. (a) rescan own row if cached best col was taken; (b) winner
// check against raw cost values of rows remaining at round start. Within-round
// col_used races are benign (conservative losers retry next round).
__global__ void __launch_bounds__(256) k_round(const float* __restrict__ cost,
                                               int* __restrict__ out, int t) {
    int r = blockIdx.x;
    if (g_row_assigned[r]) return;
    int tid = threadIdx.x;
    __shared__ u64 s_part[4];

    u64 key = g_rowbest[r];
    int c = NCOLS - 1 - (int)(key & 0xFFFFFFFFu);
    if (g_col_used[c]) {              // stale -> rescan excluding used cols
        u64 best = 0ULL;
        const float4* row = (const float4*)(cost + (size_t)r * NCOLS);
        const int4* used = (const int4*)g_col_used;
        for (int k = tid; k < NCOLS / 4; k += 256) {
            float4 v = row[k];
            int4 u = used[k];
            int c0 = k * 4;
            if (!u.x) { u64 kk = ((u64)fsort(v.x) << 32) | (u32)(NCOLS - 1 - (c0 + 0)); if (kk > best) best = kk; }
            if (!u.y) { u64 kk = ((u64)fsort(v.y) << 32) | (u32)(NCOLS - 1 - (c0 + 1)); if (kk > best) best = kk; }
            if (!u.z) { u64 kk = ((u64)fsort(v.z) << 32) | (u32)(NCOLS - 1 - (c0 + 2)); if (kk > best) best = kk; }
            if (!u.w) { u64 kk = ((u64)fsort(v.w) << 32) | (u32)(NCOLS - 1 - (c0 + 3)); if (kk > best) best = kk; }
        }
        key = block_reduce_max(best, s_part);
        if (tid == 0) g_rowbest[r] = key;
        c = NCOLS - 1 - (int)(key & 0xFFFFFFFFu);
    }

    int n = g_cnt[t];
    const int* list = g_rem[t & 1];
    u64 mine = (key & 0xFFFFFFFF00000000ULL) | (u32)(NROWS - 1 - r);
    u64 mx = 0ULL;
    for (int j = tid; j < n; j += 256) {
        int rj = list[j];
        if (rj != r) {
            float x = cost[(size_t)rj * NCOLS + c];
            u64 kj = ((u64)fsort(x) << 32) | (u32)(NROWS - 1 - rj);
            if (kj > mx) mx = kj;
        }
    }
    mx = block_reduce_max(mx, s_part);
    if (tid == 0) {
        if (mine > mx) {              // unique max at col c among survivors
            g_col_used[c] = 1;
            g_row_assigned[r] = 1;
            out[NROWS + r] = c;
        } else {
            int p = atomicAdd(&g_cnt[t + 1], 1);
            g_rem[(t + 1) & 1][p] = r;
        }
    }
}

// Correctness fallback: persistent single-block loop (normally sees n==0 or
// tiny n and exits in microseconds).
__global__ void __launch_bounds__(1024) k_finish(const float* __restrict__ cost,
                                                 int* __restrict__ out) {
    __shared__ int s_rem[2][NROWS];
    __shared__ int s_n, s_newn;
    __shared__ u64 s_part2[16];
    int tid = threadIdx.x;
    if (tid == 0) s_n = g_cnt[NROUNDS];
    __syncthreads();
    int n = s_n;
    if (n == 0) return;
    for (int i = tid; i < n; i += blockDim.x) s_rem[0][i] = g_rem[NROUNDS & 1][i];
    __syncthreads();
    int cur = 0;
    while (n > 0) {
        for (int i = 0; i < n; i++) {
            int r = s_rem[cur][i];
            u64 key = g_rowbest[r];
            int c = NCOLS - 1 - (int)(key & 0xFFFFFFFFu);
            if (g_col_used[c]) {
                u64 best = 0ULL;
                const float4* row = (const float4*)(cost + (size_t)r * NCOLS);
                for (int k = tid; k < NCOLS / 4; k += blockDim.x) {
                    float4 v = row[k];
                    int c0 = k * 4;
                    if (!g_col_used[c0 + 0]) { u64 kk = ((u64)fsort(v.x) << 32) | (u32)(NCOLS - 1 - (c0 + 0)); if (kk > best) best = kk; }
                    if (!g_col_used[c0 + 1]) { u64 kk = ((u64)fsort(v.y) << 32) | (u32)(NCOLS - 1 - (c0 + 1)); if (kk > best) best = kk; }
                    if (!g_col_used[c0 + 2]) { u64 kk = ((u64)fsort(v.z) << 32) | (u32)(NCOLS - 1 - (c0 + 2)); if (kk > best) best = kk; }
                    if (!g_col_used[c0 + 3]) { u64 kk = ((u64)fsort(v.w) << 32) | (u32)(NCOLS - 1 - (c0 + 3)); if (kk > best) best = kk; }
                }
                for (int off = 32; off; off >>= 1) {
                    u64 o = __shfl_down(best, off);
                    if (o > best) best = o;
                }
                int wave = tid >> 6;
                if ((tid & 63) == 0) s_part2[wave] = best;
                __syncthreads();
                if (tid == 0) {
                    u64 b = s_part2[0];
                    for (int w = 1; w < 16; w++) if (s_part2[w] > b) b = s_part2[w];
                    g_rowbest[r] = b;
                }
                __syncthreads();
            }
        }
        __syncthreads();
        bool win = false; int myr = -1, myc = -1;
        if (tid < n) {
            int r = s_rem[cur][tid];
            u64 key = g_rowbest[r];
            int c = NCOLS - 1 - (int)(key & 0xFFFFFFFFu);
            u64 mine = (key & 0xFFFFFFFF00000000ULL) | (u32)(NROWS - 1 - r);
            win = true;
            for (int j = 0; j < n; j++) {
                int rj = s_rem[cur][j];
                if (rj == r) continue;
                float x = cost[(size_t)rj * NCOLS + c];
                u64 kj = ((u64)fsort(x) << 32) | (u32)(NROWS - 1 - rj);
                if (kj > mine) { win = false; break; }
            }
            myr = r; myc = c;
        }
        __syncthreads();
        if (win) {
            g_col_used[myc] = 1; g_row_assigned[myr] = 1; out[NROWS + myr] = myc;
        }
        if (tid == 0) s_newn = 0;
        __syncthreads();
        if (tid < n && !win) {
            int p = atomicAdd(&s_newn, 1);
            s_rem[cur ^ 1][p] = myr;
        }
        __syncthreads();
        n = s_newn;
        cur ^= 1;
        __syncthreads();
    }
}

extern "C" void kernel_launch(void* const* d_in, const int* in_sizes, int n_in,
                              void* d_out, int out_size, void* d_ws, size_t ws_size,
                              hipStream_t stream) {
    const float* cost = (const float*)d_in[0];
    int* out = (int*)d_out;

    k_scan<<<dim3(NCB, NRB), 256, 0, stream>>>(cost);
    k_commit1<<<NROWS, 64, 0, stream>>>(out);
    k_round<<<NROWS, 256, 0, stream>>>(cost, out, 0);
    k_round<<<NROWS, 256, 0, stream>>>(cost, out, 1);
    k_finish<<<1, 1024, 0, stream>>>(cost, out);
}